// Round 21
// baseline (94.619 us; speedup 1.0000x reference)
//
#include <hip/hip_runtime.h>
#include <hip/hip_bf16.h>

#define BATCH 16
#define INP   128
#define OUP   128
#define HH    56
#define WW    56
#define HWSZ  3136
#define HID   768
#define EPSV  1e-5f

#define RWST  1992            // k23 stg row stride (dw): 8 mod 32 -> row halves de-alias banks
#define H2STR 72              // h2s elem stride (144B)

typedef __attribute__((ext_vector_type(8))) short bf16x8;
typedef __attribute__((ext_vector_type(4))) float f32x4;

__device__ __forceinline__ unsigned short f2b(float f) {
    unsigned u = __float_as_uint(f);
    return (unsigned short)((u + 0x7FFFu + ((u >> 16) & 1u)) >> 16);   // RNE
}
__device__ __forceinline__ float blo(unsigned u){ return __uint_as_float(u << 16); }
__device__ __forceinline__ float bhi(unsigned u){ return __uint_as_float(u & 0xFFFF0000u); }
__device__ __forceinline__ unsigned pkbf(float lo, float hi) {
    unsigned r;
    asm("v_cvt_pk_bf16_f32 %0, %1, %2" : "=v"(r) : "v"(lo), "v"(hi));
    return r;
}

// ---------------- prep: fold BN into bf16 weights (fragment-linear) + mask dilate ----------------
__global__ void prep(const float* __restrict__ w1, const float* __restrict__ g1,
                     const float* __restrict__ b1, const float* __restrict__ m1, const float* __restrict__ v1,
                     const float* __restrict__ wdw, const float* __restrict__ g2,
                     const float* __restrict__ b2, const float* __restrict__ m2, const float* __restrict__ v2,
                     const float* __restrict__ w2, const float* __restrict__ g3,
                     const float* __restrict__ b3, const float* __restrict__ m3, const float* __restrict__ v3,
                     const int* __restrict__ mask,
                     unsigned short* __restrict__ w1f, unsigned short* __restrict__ w2f,
                     float* __restrict__ be1o, float* __restrict__ wdsf,
                     float* __restrict__ be2o, float* __restrict__ be3o,
                     float* __restrict__ mdf, float* __restrict__ mff)
{
    int gid = blockIdx.x * blockDim.x + threadIdx.x;
    int stp = gridDim.x * blockDim.x;
    // w1 fragment-linear: [ht 48][ks 4][g 4][r16 16][e 8]
    for (int i = gid; i < HID * INP; i += stp) {
        int r = i >> 7, k = i & 127;
        float s = g1[r] * rsqrtf(v1[r] + EPSV);
        int ht = r >> 4, r16 = r & 15, ks = k >> 5, g = (k >> 3) & 3, e = k & 7;
        w1f[((((ht * 4 + ks) * 4 + g) * 16 + r16) << 3) + e] = f2b(w1[i] * s);
    }
    // w2 fragment-linear: [ot 8][ch 12][ks 2][lane 64][e 8]
    for (int i = gid; i < OUP * HID; i += stp) {
        int r = i / HID, k = i - r * HID;
        float s = g3[r] * rsqrtf(v3[r] + EPSV);
        int ot = r >> 4, r16 = r & 15, ch = k >> 6, ks = (k >> 5) & 1, g = (k >> 3) & 3, e = k & 7;
        int lane = g * 16 + r16;
        w2f[((((ot * 12 + ch) * 2 + ks) * 64 + lane) << 3) + e] = f2b(w2[i] * s);
    }
    for (int i = gid; i < HID; i += stp) {
        float s1 = g1[i] * rsqrtf(v1[i] + EPSV);
        be1o[i] = b1[i] - m1[i] * s1;
        float s2 = g2[i] * rsqrtf(v2[i] + EPSV);
        be2o[i] = b2[i] - m2[i] * s2;
    }
    for (int i = gid; i < HID * 9; i += stp) {          // tap-major [q][c], BN2 scale folded
        int q = i / HID, c = i - q * HID;
        float s2 = g2[c] * rsqrtf(v2[c] + EPSV);
        wdsf[i] = wdw[c * 9 + q] * s2;
    }
    for (int i = gid; i < OUP; i += stp) {
        float s3 = g3[i] * rsqrtf(v3[i] + EPSV);
        be3o[i] = b3[i] - m3[i] * s3;
    }
    for (int i = gid; i < BATCH * HWSZ; i += stp) {     // mf + 3x3 dilated md
        int b = i / HWSZ, p = i - b * HWSZ;
        int y = p / WW, xx = p - y * WW;
        float mf = (float)mask[i];
        float md = 0.f;
        for (int dy = -1; dy <= 1; ++dy)
            for (int dx = -1; dx <= 1; ++dx) {
                int yy = y + dy, xc = xx + dx;
                if (yy >= 0 && yy < HH && xc >= 0 && xc < WW)
                    md = fmaxf(md, (float)mask[b * HWSZ + yy * WW + xc]);
            }
        mff[i] = mf;
        mdf[i] = md;
    }
}

// ---------------- K1: expand GEMM -> h1; 2 passes x 384 hid, x staged once per block ----------------
__launch_bounds__(512, 3)
__global__ void k1_expand(const float* __restrict__ x,
                          const unsigned short* __restrict__ w1f,
                          const float* __restrict__ be1g,
                          const float* __restrict__ mdf,
                          unsigned* __restrict__ h1p)
{
    __shared__ unsigned short xs[128 * 128];   // 32 KB  bf16 x-tile [px][c] swizzled
    const int t = threadIdx.x, lane = t & 63, wv = t >> 6;
    const int g = lane >> 4, r16 = lane & 15;
    // XCD swizzle: 800 = 8*100; hb-siblings adjacent -> share x tile in L2
    const int pid = blockIdx.x;
    const int l = (pid & 7) * 100 + (pid >> 3);
    const int hb = l & 1;
    const int rest = l >> 1;
    const int pb = rest % 25;
    const int b  = rest / 25;
    const int p0 = pb * 128;
    const int whid = wv & 3;       // 4 hid slices of 96 within the 384-hid pass
    const int wpx  = wv >> 2;      // 2 px halves of 64

    // stage x tile (fp32 -> bf16), coalesced along p
    for (int rep = 0; rep < 8; ++rep) {
        int id = t + rep * 512;
        int px = id & 127, c4 = id >> 7;
        int p = p0 + px;
        ushort4 u; u.x = 0; u.y = 0; u.z = 0; u.w = 0;
        if (p < HWSZ) {
            const float* xp = x + ((size_t)(b * INP + c4 * 4)) * HWSZ + p;
            unsigned lo = pkbf(xp[0], xp[HWSZ]);
            unsigned hi = pkbf(xp[2 * HWSZ], xp[3 * HWSZ]);
            u.x = (unsigned short)lo; u.y = (unsigned short)(lo >> 16);
            u.z = (unsigned short)hi; u.w = (unsigned short)(hi >> 16);
        }
        *(ushort4*)&xs[px * 128 + (((c4 >> 1) ^ (px & 15)) << 3) + ((c4 & 1) << 2)] = u;
    }
    __syncthreads();

    f32x4 acc[6][4];
    #pragma unroll
    for (int mt = 0; mt < 6; ++mt)
        #pragma unroll
        for (int nt = 0; nt < 4; ++nt) {
            acc[mt][nt][0] = 0.f; acc[mt][nt][1] = 0.f;
            acc[mt][nt][2] = 0.f; acc[mt][nt][3] = 0.f;
        }
    const int hbase = hb * 384 + whid * 96;   // 96 hid (6 m-tiles) per wave
    const int htb = hbase >> 4;

    #pragma unroll
    for (int ks = 0; ks < 4; ++ks) {
        bf16x8 af[6];
        #pragma unroll
        for (int mt = 0; mt < 6; ++mt)     // coalesced 1KB wave-loads
            af[mt] = *(const bf16x8*)&w1f[((((htb + mt) * 4 + ks) * 64) + lane) << 3];
        #pragma unroll
        for (int nt = 0; nt < 4; ++nt) {
            int px = wpx * 64 + nt * 16 + r16;
            bf16x8 bf = *(const bf16x8*)&xs[px * 128 + (((ks * 4 + g) ^ r16) << 3)];
            #pragma unroll
            for (int mt = 0; mt < 6; ++mt)
                acc[mt][nt] = __builtin_amdgcn_mfma_f32_16x16x32_bf16(af[mt], bf, acc[mt][nt], 0, 0, 0);
        }
    }

    // epilogue: BN1 bias + relu6 + md, pack hid-pairs, coalesced dword stores
    #pragma unroll
    for (int nt = 0; nt < 4; ++nt) {
        const int pg = p0 + wpx * 64 + nt * 16;
        if (pg >= HWSZ) continue;              // wave-uniform
        const int p = pg + r16;
        const float md = mdf[b * HWSZ + p];
        #pragma unroll
        for (int mt = 0; mt < 6; ++mt) {
            const float4 be4 = *(const float4*)&be1g[hbase + mt * 16 + g * 4];
            f32x4 a = acc[mt][nt];
            float v0 = fminf(fmaxf(a[0] + be4.x, 0.f), 6.f) * md;
            float v1 = fminf(fmaxf(a[1] + be4.y, 0.f), 6.f) * md;
            float v2 = fminf(fmaxf(a[2] + be4.z, 0.f), 6.f) * md;
            float v3 = fminf(fmaxf(a[3] + be4.w, 0.f), 6.f) * md;
            const int c2 = (hbase >> 1) + mt * 8 + g * 2;
            const size_t ad = (size_t)(b * 384 + c2) * HWSZ + p;
            h1p[ad] = pkbf(v0, v1);
            h1p[ad + HWSZ] = pkbf(v2, v3);
        }
    }
}

// ---------------- K23: r13 structure + s_setprio around P MFMA cluster (T5) — r20 proven ----------------
__launch_bounds__(512, 4)
__global__ void k23(const unsigned* __restrict__ h1p,
                    const unsigned short* __restrict__ w2f,
                    const float* __restrict__ wdsf,
                    const float* __restrict__ be2g,
                    const float* __restrict__ be3g,
                    const float* __restrict__ mff,
                    const float* __restrict__ x,
                    float* __restrict__ out)
{
    __shared__ unsigned stg[4 * RWST];           // 31872 B  h1 rows [row 4][cp 32 x 62 dw]
    __shared__ unsigned short h2s[112 * H2STR];  // 16128 B  h2 [px][c] swizzled
    __shared__ float mfv_[112];                  //   448 B

    const int t = threadIdx.x, lane = t & 63, wv = t >> 6;
    const int g = lane >> 4, r16 = lane & 15;
    const int pid = blockIdx.x;
    const int l = (pid & 7) * 56 + (pid >> 3);   // XCD swizzle (448 = 8*56)
    const int strip = l % 28, b = l / 28;
    const int y0 = strip * 2, p0 = strip * 112;

    // ---------------- prologue ----------------
    if (t < 112) mfv_[t] = mff[b * HWSZ + p0 + t];
    if (t >= 128 && t < 384) {   // zero stg edge dwords (px=-1 at off 1, px=56 at off 58)
        int i = t - 128;
        int cp = i & 31, rs = (i >> 5) & 3, side = (i >> 7) & 1;
        stg[rs * RWST + cp * 62 + (side ? 58 : 1)] = 0;
    }

    // T14 stage state: 1792 tasks = cp32 x row4 x px4_14
    int gaddr[4], laddr[4]; bool gval[4], wval[4];
    #pragma unroll
    for (int rep = 0; rep < 4; ++rep) {
        const int id = t + rep * 512;
        const int rr  = (id * 4682) >> 16;            // id/14
        const int px4 = id - rr * 14;
        const int row = rr & 3, cp = rr >> 2;
        const int gy = y0 - 1 + row;
        wval[rep] = id < 1792;
        gval[rep] = wval[rep] && gy >= 0 && gy < HH;
        gaddr[rep] = (b * 384 + cp) * HWSZ + gy * WW + px4 * 4;
        laddr[rep] = row * RWST + cp * 62 + 2 + px4 * 4;
    }
    uint4 sreg[4];

    auto issueLoads = [&]() {
        #pragma unroll
        for (int rep = 0; rep < 4; ++rep) {
            uint4 u; u.x = 0; u.y = 0; u.z = 0; u.w = 0;
            if (gval[rep]) u = *(const uint4*)&h1p[gaddr[rep]];
            sreg[rep] = u;
            gaddr[rep] += 32 * HWSZ;                  // next chunk (+32 cp)
        }
    };
    auto stageWrite = [&]() {
        #pragma unroll
        for (int rep = 0; rep < 4; ++rep) {
            if (wval[rep]) {
                unsigned* s = &stg[laddr[rep]];
                uint2 a; a.x = sreg[rep].x; a.y = sreg[rep].y;
                uint2 c; c.x = sreg[rep].z; c.y = sreg[rep].w;
                *(uint2*)(s) = a;
                *(uint2*)(s + 2) = c;
            }
        }
    };

    // DW mapping: thread -> (cp 32, row2 2, q 8); 2 paired channels x 7 px each
    const int cp_c = t & 31, row2 = (t >> 5) & 1, q = t >> 6;   // q == wave id
    unsigned* const h2d = (unsigned*)h2s;

    auto phaseDW = [&](int ch) {
        const float2 be2 = *(const float2*)&be2g[ch * 64 + 2 * cp_c];
        float accL[7], accH[7];
        #pragma unroll
        for (int j = 0; j < 7; ++j) { accL[j] = be2.x; accH[j] = be2.y; }
        #pragma unroll
        for (int dy = 0; dy < 3; ++dy) {
            const float2 wt0 = *(const float2*)&wdsf[(dy * 3 + 0) * HID + ch * 64 + 2 * cp_c];
            const float2 wt1 = *(const float2*)&wdsf[(dy * 3 + 1) * HID + ch * 64 + 2 * cp_c];
            const float2 wt2 = *(const float2*)&wdsf[(dy * 3 + 2) * HID + ch * 64 + 2 * cp_c];
            const unsigned* rp = &stg[(row2 + dy) * RWST + cp_c * 62 + 1 + q * 7];
            float pL[9], pH[9];
            #pragma unroll
            for (int k = 0; k < 9; ++k) {
                unsigned u = rp[k];
                pL[k] = blo(u); pH[k] = bhi(u);
            }
            #pragma unroll
            for (int j = 0; j < 7; ++j) {
                accL[j] += pL[j] * wt0.x + pL[j + 1] * wt1.x + pL[j + 2] * wt2.x;
                accH[j] += pH[j] * wt0.y + pH[j + 1] * wt1.y + pH[j + 2] * wt2.y;
            }
        }
        #pragma unroll
        for (int j = 0; j < 7; ++j) {
            const int px = row2 * 56 + q * 7 + j;
            const float mv = mfv_[px];
            float vL = __builtin_amdgcn_fmed3f(accL[j], 0.f, 6.f) * mv;
            float vH = __builtin_amdgcn_fmed3f(accH[j], 0.f, 6.f) * mv;
            // full-dword write at P-read-compatible slot: octet (cp>>2)^(px&7), dword (cp&3)
            h2d[px * 36 + (((cp_c >> 2) ^ (px & 7)) << 2) + (cp_c & 3)] = pkbf(vL, vH);
        }
    };

    f32x4 pacc[7];
    #pragma unroll
    for (int nt = 0; nt < 7; ++nt) {
        pacc[nt][0] = 0.f; pacc[nt][1] = 0.f; pacc[nt][2] = 0.f; pacc[nt][3] = 0.f;
    }

    auto phaseP = [&](int ch) {
        __builtin_amdgcn_s_setprio(1);        // T5: favor MFMA-phase waves vs co-resident DW waves
        #pragma unroll
        for (int ks = 0; ks < 2; ++ks) {
            const bf16x8 pw = *(const bf16x8*)&w2f[((((wv * 12 + ch) * 2 + ks) * 64) + lane) << 3];
            #pragma unroll
            for (int nt = 0; nt < 7; ++nt) {
                const int px = nt * 16 + r16;
                const bf16x8 hb = *(const bf16x8*)&h2s[px * H2STR + (((ks * 4 + g) ^ (px & 7)) << 3)];
                pacc[nt] = __builtin_amdgcn_mfma_f32_16x16x32_bf16(pw, hb, pacc[nt], 0, 0, 0);
            }
        }
        __builtin_amdgcn_s_setprio(0);
    };

    // ---- main loop: loads for ch+1 fly under DW(ch); write lands under P(ch) ----
    issueLoads();
    stageWrite();
    __syncthreads();
    for (int ch = 0; ch < 12; ++ch) {
        if (ch + 1 < 12) issueLoads();
        phaseDW(ch);
        __syncthreads();                      // stg reads done; h2s written
        if (ch + 1 < 12) stageWrite();
        phaseP(ch);
        __syncthreads();                      // stg ready; h2s free
    }

    // ---- epilogue: out = x + (proj + be3) * mf ----
    {
        const int ob = wv * 16 + g * 4;
        const float4 be4 = *(const float4*)&be3g[ob];
        #pragma unroll
        for (int nt = 0; nt < 7; ++nt) {
            const int px = nt * 16 + r16;
            const float mv = mfv_[px];
            const size_t base = (size_t)(b * OUP + ob) * HWSZ + p0 + px;
            out[base]            = x[base]            + (pacc[nt][0] + be4.x) * mv;
            out[base + HWSZ]     = x[base + HWSZ]     + (pacc[nt][1] + be4.y) * mv;
            out[base + 2 * HWSZ] = x[base + 2 * HWSZ] + (pacc[nt][2] + be4.z) * mv;
            out[base + 3 * HWSZ] = x[base + 3 * HWSZ] + (pacc[nt][3] + be4.w) * mv;
        }
    }
}

extern "C" void kernel_launch(void* const* d_in, const int* in_sizes, int n_in,
                              void* d_out, int out_size, void* d_ws, size_t ws_size,
                              hipStream_t stream) {
    (void)in_sizes; (void)n_in; (void)out_size; (void)ws_size;
    const float* x   = (const float*)d_in[0];
    const float* w1  = (const float*)d_in[1];
    const float* g1  = (const float*)d_in[2];
    const float* b1  = (const float*)d_in[3];
    const float* m1  = (const float*)d_in[4];
    const float* v1  = (const float*)d_in[5];
    const float* wdw = (const float*)d_in[6];
    const float* g2  = (const float*)d_in[7];
    const float* b2  = (const float*)d_in[8];
    const float* m2  = (const float*)d_in[9];
    const float* v2  = (const float*)d_in[10];
    const float* w2  = (const float*)d_in[11];
    const float* g3  = (const float*)d_in[12];
    const float* b3  = (const float*)d_in[13];
    const float* m3  = (const float*)d_in[14];
    const float* v3  = (const float*)d_in[15];
    const int*  mask = (const int*)d_in[16];
    float* out = (float*)d_out;

    char* ws = (char*)d_ws;
    unsigned short* w1f = (unsigned short*)ws;                 // 196608 B
    unsigned short* w2f = (unsigned short*)(ws + 196608);      // 196608 B
    float* be1o = (float*)(ws + 393216);                       // 3072 B
    float* wdsf = (float*)(ws + 396288);                       // 27648 B  [9][768]
    float* be2o = (float*)(ws + 423936);                       // 3072 B
    float* be3o = (float*)(ws + 427008);                       // 512 B
    float* mdf  = (float*)(ws + 427520);                       // 200704 B
    float* mff  = (float*)(ws + 628224);                       // 200704 B
    unsigned* h1p = (unsigned*)(ws + 828928);                  // 77070336 B (bf16 pairs)

    prep<<<256, 256, 0, stream>>>(w1, g1, b1, m1, v1, wdw, g2, b2, m2, v2,
                                  w2, g3, b3, m3, v3, mask,
                                  w1f, w2f, be1o, wdsf, be2o, be3o, mdf, mff);
    // K1: 2 hb-passes x 25 px-blocks x 16 batches = 800 blocks
    k1_expand<<<dim3(800), 512, 0, stream>>>(x, w1f, be1o, mdf, h1p);
    k23<<<dim3(448), 512, 0, stream>>>(h1p, w2f, wdsf, be2o, be3o, mff, x, out);
}

// Round 22
// 87.954 us; speedup vs baseline: 1.0758x; 1.0758x over previous
//
#include <hip/hip_runtime.h>
#include <hip/hip_bf16.h>

#define BATCH 16
#define INP   128
#define OUP   128
#define HH    56
#define WW    56
#define HWSZ  3136
#define HID   768
#define EPSV  1e-5f

#define RWST  1992            // k23 stg row stride (dw): 8 mod 32 -> row halves de-alias banks
#define H2STR 72              // h2s elem stride (144B)

typedef __attribute__((ext_vector_type(8))) short bf16x8;
typedef __attribute__((ext_vector_type(4))) float f32x4;

__device__ __forceinline__ unsigned short f2b(float f) {
    unsigned u = __float_as_uint(f);
    return (unsigned short)((u + 0x7FFFu + ((u >> 16) & 1u)) >> 16);   // RNE
}
__device__ __forceinline__ float blo(unsigned u){ return __uint_as_float(u << 16); }
__device__ __forceinline__ float bhi(unsigned u){ return __uint_as_float(u & 0xFFFF0000u); }
__device__ __forceinline__ unsigned pkbf(float lo, float hi) {
    unsigned r;
    asm("v_cvt_pk_bf16_f32 %0, %1, %2" : "=v"(r) : "v"(lo), "v"(hi));
    return r;
}

// ---------------- prep: fold BN into bf16 weights (fragment-linear) + mask dilate ----------------
__global__ void prep(const float* __restrict__ w1, const float* __restrict__ g1,
                     const float* __restrict__ b1, const float* __restrict__ m1, const float* __restrict__ v1,
                     const float* __restrict__ wdw, const float* __restrict__ g2,
                     const float* __restrict__ b2, const float* __restrict__ m2, const float* __restrict__ v2,
                     const float* __restrict__ w2, const float* __restrict__ g3,
                     const float* __restrict__ b3, const float* __restrict__ m3, const float* __restrict__ v3,
                     const int* __restrict__ mask,
                     unsigned short* __restrict__ w1f, unsigned short* __restrict__ w2f,
                     float* __restrict__ be1o, float* __restrict__ wdsf,
                     float* __restrict__ be2o, float* __restrict__ be3o,
                     float* __restrict__ mdf, float* __restrict__ mff)
{
    int gid = blockIdx.x * blockDim.x + threadIdx.x;
    int stp = gridDim.x * blockDim.x;
    // w1 fragment-linear: [ht 48][ks 4][g 4][r16 16][e 8]
    for (int i = gid; i < HID * INP; i += stp) {
        int r = i >> 7, k = i & 127;
        float s = g1[r] * rsqrtf(v1[r] + EPSV);
        int ht = r >> 4, r16 = r & 15, ks = k >> 5, g = (k >> 3) & 3, e = k & 7;
        w1f[((((ht * 4 + ks) * 4 + g) * 16 + r16) << 3) + e] = f2b(w1[i] * s);
    }
    // w2 fragment-linear: [ot 8][ch 12][ks 2][lane 64][e 8]
    for (int i = gid; i < OUP * HID; i += stp) {
        int r = i / HID, k = i - r * HID;
        float s = g3[r] * rsqrtf(v3[r] + EPSV);
        int ot = r >> 4, r16 = r & 15, ch = k >> 6, ks = (k >> 5) & 1, g = (k >> 3) & 3, e = k & 7;
        int lane = g * 16 + r16;
        w2f[((((ot * 12 + ch) * 2 + ks) * 64 + lane) << 3) + e] = f2b(w2[i] * s);
    }
    for (int i = gid; i < HID; i += stp) {
        float s1 = g1[i] * rsqrtf(v1[i] + EPSV);
        be1o[i] = b1[i] - m1[i] * s1;
        float s2 = g2[i] * rsqrtf(v2[i] + EPSV);
        be2o[i] = b2[i] - m2[i] * s2;
    }
    for (int i = gid; i < HID * 9; i += stp) {          // tap-major [q][c], BN2 scale folded
        int q = i / HID, c = i - q * HID;
        float s2 = g2[c] * rsqrtf(v2[c] + EPSV);
        wdsf[i] = wdw[c * 9 + q] * s2;
    }
    for (int i = gid; i < OUP; i += stp) {
        float s3 = g3[i] * rsqrtf(v3[i] + EPSV);
        be3o[i] = b3[i] - m3[i] * s3;
    }
    for (int i = gid; i < BATCH * HWSZ; i += stp) {     // mf + 3x3 dilated md
        int b = i / HWSZ, p = i - b * HWSZ;
        int y = p / WW, xx = p - y * WW;
        float mf = (float)mask[i];
        float md = 0.f;
        for (int dy = -1; dy <= 1; ++dy)
            for (int dx = -1; dx <= 1; ++dx) {
                int yy = y + dy, xc = xx + dx;
                if (yy >= 0 && yy < HH && xc >= 0 && xc < WW)
                    md = fmaxf(md, (float)mask[b * HWSZ + yy * WW + xc]);
            }
        mff[i] = mf;
        mdf[i] = md;
    }
}

// ---------------- K1: expand GEMM -> h1 (bf16 pair-interleaved [b][c/2][p]) — r10/r13 proven ----------------
__launch_bounds__(512, 4)
__global__ void k1_expand(const float* __restrict__ x,
                          const unsigned short* __restrict__ w1f,
                          const float* __restrict__ be1g,
                          const float* __restrict__ mdf,
                          unsigned* __restrict__ h1p)
{
    __shared__ unsigned short xs[128 * 128];   // 32 KB  bf16 x-tile [px][c] swizzled
    const int t = threadIdx.x, lane = t & 63, wv = t >> 6;
    const int g = lane >> 4, r16 = lane & 15;
    const int pid = blockIdx.x;
    const int l = (pid & 7) * 150 + (pid >> 3);
    const int hb = l % 3;
    const int pb = (l / 3) % 25;
    const int b  = l / 75;
    const int p0 = pb * 128;
    const int whid = wv & 3;
    const int wpx  = wv >> 2;

    for (int rep = 0; rep < 8; ++rep) {
        int id = t + rep * 512;
        int px = id & 127, c4 = id >> 7;
        int p = p0 + px;
        ushort4 u; u.x = 0; u.y = 0; u.z = 0; u.w = 0;
        if (p < HWSZ) {
            const float* xp = x + ((size_t)(b * INP + c4 * 4)) * HWSZ + p;
            unsigned lo = pkbf(xp[0], xp[HWSZ]);
            unsigned hi = pkbf(xp[2 * HWSZ], xp[3 * HWSZ]);
            u.x = (unsigned short)lo; u.y = (unsigned short)(lo >> 16);
            u.z = (unsigned short)hi; u.w = (unsigned short)(hi >> 16);
        }
        *(ushort4*)&xs[px * 128 + (((c4 >> 1) ^ (px & 15)) << 3) + ((c4 & 1) << 2)] = u;
    }
    __syncthreads();

    f32x4 acc[4][4];
    #pragma unroll
    for (int mt = 0; mt < 4; ++mt)
        #pragma unroll
        for (int nt = 0; nt < 4; ++nt) {
            acc[mt][nt][0] = 0.f; acc[mt][nt][1] = 0.f;
            acc[mt][nt][2] = 0.f; acc[mt][nt][3] = 0.f;
        }
    const int hbase = hb * 256 + whid * 64;
    const int htb = hbase >> 4;

    #pragma unroll
    for (int ks = 0; ks < 4; ++ks) {
        bf16x8 af[4];
        #pragma unroll
        for (int mt = 0; mt < 4; ++mt)
            af[mt] = *(const bf16x8*)&w1f[((((htb + mt) * 4 + ks) * 64) + lane) << 3];
        #pragma unroll
        for (int nt = 0; nt < 4; ++nt) {
            int px = wpx * 64 + nt * 16 + r16;
            bf16x8 bf = *(const bf16x8*)&xs[px * 128 + (((ks * 4 + g) ^ r16) << 3)];
            #pragma unroll
            for (int mt = 0; mt < 4; ++mt)
                acc[mt][nt] = __builtin_amdgcn_mfma_f32_16x16x32_bf16(af[mt], bf, acc[mt][nt], 0, 0, 0);
        }
    }

    #pragma unroll
    for (int nt = 0; nt < 4; ++nt) {
        const int pg = p0 + wpx * 64 + nt * 16;
        if (pg >= HWSZ) continue;
        const int p = pg + r16;
        const float md = mdf[b * HWSZ + p];
        #pragma unroll
        for (int mt = 0; mt < 4; ++mt) {
            const float4 be4 = *(const float4*)&be1g[hbase + mt * 16 + g * 4];
            f32x4 a = acc[mt][nt];
            float v0 = fminf(fmaxf(a[0] + be4.x, 0.f), 6.f) * md;
            float v1 = fminf(fmaxf(a[1] + be4.y, 0.f), 6.f) * md;
            float v2 = fminf(fmaxf(a[2] + be4.z, 0.f), 6.f) * md;
            float v3 = fminf(fmaxf(a[3] + be4.w, 0.f), 6.f) * md;
            const int c2 = (hbase >> 1) + mt * 8 + g * 2;
            const size_t ad = (size_t)(b * 384 + c2) * HWSZ + p;
            h1p[ad] = pkbf(v0, v1);
            h1p[ad + HWSZ] = pkbf(v2, v3);
        }
    }
}

// ---------------- K23: r13 structure + s_setprio around P MFMA cluster (T5) ----------------
__launch_bounds__(512, 4)
__global__ void k23(const unsigned* __restrict__ h1p,
                    const unsigned short* __restrict__ w2f,
                    const float* __restrict__ wdsf,
                    const float* __restrict__ be2g,
                    const float* __restrict__ be3g,
                    const float* __restrict__ mff,
                    const float* __restrict__ x,
                    float* __restrict__ out)
{
    __shared__ unsigned stg[4 * RWST];           // 31872 B  h1 rows [row 4][cp 32 x 62 dw]
    __shared__ unsigned short h2s[112 * H2STR];  // 16128 B  h2 [px][c] swizzled
    __shared__ float mfv_[112];                  //   448 B

    const int t = threadIdx.x, lane = t & 63, wv = t >> 6;
    const int g = lane >> 4, r16 = lane & 15;
    const int pid = blockIdx.x;
    const int l = (pid & 7) * 56 + (pid >> 3);   // XCD swizzle (448 = 8*56)
    const int strip = l % 28, b = l / 28;
    const int y0 = strip * 2, p0 = strip * 112;

    // ---------------- prologue ----------------
    if (t < 112) mfv_[t] = mff[b * HWSZ + p0 + t];
    if (t >= 128 && t < 384) {   // zero stg edge dwords (px=-1 at off 1, px=56 at off 58)
        int i = t - 128;
        int cp = i & 31, rs = (i >> 5) & 3, side = (i >> 7) & 1;
        stg[rs * RWST + cp * 62 + (side ? 58 : 1)] = 0;
    }

    // T14 stage state: 1792 tasks = cp32 x row4 x px4_14
    int gaddr[4], laddr[4]; bool gval[4], wval[4];
    #pragma unroll
    for (int rep = 0; rep < 4; ++rep) {
        const int id = t + rep * 512;
        const int rr  = (id * 4682) >> 16;            // id/14
        const int px4 = id - rr * 14;
        const int row = rr & 3, cp = rr >> 2;
        const int gy = y0 - 1 + row;
        wval[rep] = id < 1792;
        gval[rep] = wval[rep] && gy >= 0 && gy < HH;
        gaddr[rep] = (b * 384 + cp) * HWSZ + gy * WW + px4 * 4;
        laddr[rep] = row * RWST + cp * 62 + 2 + px4 * 4;
    }
    uint4 sreg[4];

    auto issueLoads = [&]() {
        #pragma unroll
        for (int rep = 0; rep < 4; ++rep) {
            uint4 u; u.x = 0; u.y = 0; u.z = 0; u.w = 0;
            if (gval[rep]) u = *(const uint4*)&h1p[gaddr[rep]];
            sreg[rep] = u;
            gaddr[rep] += 32 * HWSZ;                  // next chunk (+32 cp)
        }
    };
    auto stageWrite = [&]() {
        #pragma unroll
        for (int rep = 0; rep < 4; ++rep) {
            if (wval[rep]) {
                unsigned* s = &stg[laddr[rep]];
                uint2 a; a.x = sreg[rep].x; a.y = sreg[rep].y;
                uint2 c; c.x = sreg[rep].z; c.y = sreg[rep].w;
                *(uint2*)(s) = a;
                *(uint2*)(s + 2) = c;
            }
        }
    };

    // DW mapping: thread -> (cp 32, row2 2, q 8); 2 paired channels x 7 px each
    const int cp_c = t & 31, row2 = (t >> 5) & 1, q = t >> 6;   // q == wave id
    unsigned* const h2d = (unsigned*)h2s;

    auto phaseDW = [&](int ch) {
        const float2 be2 = *(const float2*)&be2g[ch * 64 + 2 * cp_c];
        float accL[7], accH[7];
        #pragma unroll
        for (int j = 0; j < 7; ++j) { accL[j] = be2.x; accH[j] = be2.y; }
        #pragma unroll
        for (int dy = 0; dy < 3; ++dy) {
            const float2 wt0 = *(const float2*)&wdsf[(dy * 3 + 0) * HID + ch * 64 + 2 * cp_c];
            const float2 wt1 = *(const float2*)&wdsf[(dy * 3 + 1) * HID + ch * 64 + 2 * cp_c];
            const float2 wt2 = *(const float2*)&wdsf[(dy * 3 + 2) * HID + ch * 64 + 2 * cp_c];
            const unsigned* rp = &stg[(row2 + dy) * RWST + cp_c * 62 + 1 + q * 7];
            float pL[9], pH[9];
            #pragma unroll
            for (int k = 0; k < 9; ++k) {
                unsigned u = rp[k];
                pL[k] = blo(u); pH[k] = bhi(u);
            }
            #pragma unroll
            for (int j = 0; j < 7; ++j) {
                accL[j] += pL[j] * wt0.x + pL[j + 1] * wt1.x + pL[j + 2] * wt2.x;
                accH[j] += pH[j] * wt0.y + pH[j + 1] * wt1.y + pH[j + 2] * wt2.y;
            }
        }
        #pragma unroll
        for (int j = 0; j < 7; ++j) {
            const int px = row2 * 56 + q * 7 + j;
            const float mv = mfv_[px];
            float vL = __builtin_amdgcn_fmed3f(accL[j], 0.f, 6.f) * mv;
            float vH = __builtin_amdgcn_fmed3f(accH[j], 0.f, 6.f) * mv;
            // full-dword write at P-read-compatible slot: octet (cp>>2)^(px&7), dword (cp&3)
            h2d[px * 36 + (((cp_c >> 2) ^ (px & 7)) << 2) + (cp_c & 3)] = pkbf(vL, vH);
        }
    };

    f32x4 pacc[7];
    #pragma unroll
    for (int nt = 0; nt < 7; ++nt) {
        pacc[nt][0] = 0.f; pacc[nt][1] = 0.f; pacc[nt][2] = 0.f; pacc[nt][3] = 0.f;
    }

    auto phaseP = [&](int ch) {
        __builtin_amdgcn_s_setprio(1);        // T5: favor MFMA-phase waves vs co-resident DW waves
        #pragma unroll
        for (int ks = 0; ks < 2; ++ks) {
            const bf16x8 pw = *(const bf16x8*)&w2f[((((wv * 12 + ch) * 2 + ks) * 64) + lane) << 3];
            #pragma unroll
            for (int nt = 0; nt < 7; ++nt) {
                const int px = nt * 16 + r16;
                const bf16x8 hb = *(const bf16x8*)&h2s[px * H2STR + (((ks * 4 + g) ^ (px & 7)) << 3)];
                pacc[nt] = __builtin_amdgcn_mfma_f32_16x16x32_bf16(pw, hb, pacc[nt], 0, 0, 0);
            }
        }
        __builtin_amdgcn_s_setprio(0);
    };

    // ---- main loop: loads for ch+1 fly under DW(ch); write lands under P(ch) ----
    issueLoads();
    stageWrite();
    __syncthreads();
    for (int ch = 0; ch < 12; ++ch) {
        if (ch + 1 < 12) issueLoads();
        phaseDW(ch);
        __syncthreads();                      // stg reads done; h2s written
        if (ch + 1 < 12) stageWrite();
        phaseP(ch);
        __syncthreads();                      // stg ready; h2s free
    }

    // ---- epilogue: out = x + (proj + be3) * mf ----
    {
        const int ob = wv * 16 + g * 4;
        const float4 be4 = *(const float4*)&be3g[ob];
        #pragma unroll
        for (int nt = 0; nt < 7; ++nt) {
            const int px = nt * 16 + r16;
            const float mv = mfv_[px];
            const size_t base = (size_t)(b * OUP + ob) * HWSZ + p0 + px;
            out[base]            = x[base]            + (pacc[nt][0] + be4.x) * mv;
            out[base + HWSZ]     = x[base + HWSZ]     + (pacc[nt][1] + be4.y) * mv;
            out[base + 2 * HWSZ] = x[base + 2 * HWSZ] + (pacc[nt][2] + be4.z) * mv;
            out[base + 3 * HWSZ] = x[base + 3 * HWSZ] + (pacc[nt][3] + be4.w) * mv;
        }
    }
}

extern "C" void kernel_launch(void* const* d_in, const int* in_sizes, int n_in,
                              void* d_out, int out_size, void* d_ws, size_t ws_size,
                              hipStream_t stream) {
    (void)in_sizes; (void)n_in; (void)out_size; (void)ws_size;
    const float* x   = (const float*)d_in[0];
    const float* w1  = (const float*)d_in[1];
    const float* g1  = (const float*)d_in[2];
    const float* b1  = (const float*)d_in[3];
    const float* m1  = (const float*)d_in[4];
    const float* v1  = (const float*)d_in[5];
    const float* wdw = (const float*)d_in[6];
    const float* g2  = (const float*)d_in[7];
    const float* b2  = (const float*)d_in[8];
    const float* m2  = (const float*)d_in[9];
    const float* v2  = (const float*)d_in[10];
    const float* w2  = (const float*)d_in[11];
    const float* g3  = (const float*)d_in[12];
    const float* b3  = (const float*)d_in[13];
    const float* m3  = (const float*)d_in[14];
    const float* v3  = (const float*)d_in[15];
    const int*  mask = (const int*)d_in[16];
    float* out = (float*)d_out;

    char* ws = (char*)d_ws;
    unsigned short* w1f = (unsigned short*)ws;                 // 196608 B
    unsigned short* w2f = (unsigned short*)(ws + 196608);      // 196608 B
    float* be1o = (float*)(ws + 393216);                       // 3072 B
    float* wdsf = (float*)(ws + 396288);                       // 27648 B  [9][768]
    float* be2o = (float*)(ws + 423936);                       // 3072 B
    float* be3o = (float*)(ws + 427008);                       // 512 B
    float* mdf  = (float*)(ws + 427520);                       // 200704 B
    float* mff  = (float*)(ws + 628224);                       // 200704 B
    unsigned* h1p = (unsigned*)(ws + 828928);                  // 77070336 B (bf16 pairs)

    prep<<<256, 256, 0, stream>>>(w1, g1, b1, m1, v1, wdw, g2, b2, m2, v2,
                                  w2, g3, b3, m3, v3, mask,
                                  w1f, w2f, be1o, wdsf, be2o, be3o, mdf, mff);
    k1_expand<<<dim3(1200), 512, 0, stream>>>(x, w1f, be1o, mdf, h1p);
    k23<<<dim3(448), 512, 0, stream>>>(h1p, w2f, wdsf, be2o, be3o, mff, x, out);
}

// Round 23
// 87.894 us; speedup vs baseline: 1.0765x; 1.0007x over previous
//
#include <hip/hip_runtime.h>
#include <hip/hip_bf16.h>

#define BATCH 16
#define INP   128
#define OUP   128
#define HH    56
#define WW    56
#define HWSZ  3136
#define HID   768
#define EPSV  1e-5f

#define RWST  1992            // k23 stg row stride (dw): 8 mod 32 -> row halves de-alias banks
#define H2STR 72              // h2s elem stride (144B)

typedef __attribute__((ext_vector_type(8))) short bf16x8;
typedef __attribute__((ext_vector_type(4))) float f32x4;

__device__ __forceinline__ unsigned short f2b(float f) {
    unsigned u = __float_as_uint(f);
    return (unsigned short)((u + 0x7FFFu + ((u >> 16) & 1u)) >> 16);   // RNE
}
__device__ __forceinline__ float blo(unsigned u){ return __uint_as_float(u << 16); }
__device__ __forceinline__ float bhi(unsigned u){ return __uint_as_float(u & 0xFFFF0000u); }
__device__ __forceinline__ unsigned pkbf(float lo, float hi) {
    unsigned r;
    asm("v_cvt_pk_bf16_f32 %0, %1, %2" : "=v"(r) : "v"(lo), "v"(hi));
    return r;
}

// ---------------- prep: fold BN into bf16 weights (fragment-linear) + mask dilate ----------------
__global__ void prep(const float* __restrict__ w1, const float* __restrict__ g1,
                     const float* __restrict__ b1, const float* __restrict__ m1, const float* __restrict__ v1,
                     const float* __restrict__ wdw, const float* __restrict__ g2,
                     const float* __restrict__ b2, const float* __restrict__ m2, const float* __restrict__ v2,
                     const float* __restrict__ w2, const float* __restrict__ g3,
                     const float* __restrict__ b3, const float* __restrict__ m3, const float* __restrict__ v3,
                     const int* __restrict__ mask,
                     unsigned short* __restrict__ w1f, unsigned short* __restrict__ w2f,
                     float* __restrict__ be1o, float* __restrict__ wdsf,
                     float* __restrict__ be2o, float* __restrict__ be3o,
                     float* __restrict__ mdf, float* __restrict__ mff)
{
    int gid = blockIdx.x * blockDim.x + threadIdx.x;
    int stp = gridDim.x * blockDim.x;
    // w1 fragment-linear: [ht 48][ks 4][g 4][r16 16][e 8]
    for (int i = gid; i < HID * INP; i += stp) {
        int r = i >> 7, k = i & 127;
        float s = g1[r] * rsqrtf(v1[r] + EPSV);
        int ht = r >> 4, r16 = r & 15, ks = k >> 5, g = (k >> 3) & 3, e = k & 7;
        w1f[((((ht * 4 + ks) * 4 + g) * 16 + r16) << 3) + e] = f2b(w1[i] * s);
    }
    // w2 fragment-linear: [ot 8][ch 12][ks 2][lane 64][e 8]
    for (int i = gid; i < OUP * HID; i += stp) {
        int r = i / HID, k = i - r * HID;
        float s = g3[r] * rsqrtf(v3[r] + EPSV);
        int ot = r >> 4, r16 = r & 15, ch = k >> 6, ks = (k >> 5) & 1, g = (k >> 3) & 3, e = k & 7;
        int lane = g * 16 + r16;
        w2f[((((ot * 12 + ch) * 2 + ks) * 64 + lane) << 3) + e] = f2b(w2[i] * s);
    }
    for (int i = gid; i < HID; i += stp) {
        float s1 = g1[i] * rsqrtf(v1[i] + EPSV);
        be1o[i] = b1[i] - m1[i] * s1;
        float s2 = g2[i] * rsqrtf(v2[i] + EPSV);
        be2o[i] = b2[i] - m2[i] * s2;
    }
    for (int i = gid; i < HID * 9; i += stp) {          // tap-major [q][c], BN2 scale folded
        int q = i / HID, c = i - q * HID;
        float s2 = g2[c] * rsqrtf(v2[c] + EPSV);
        wdsf[i] = wdw[c * 9 + q] * s2;
    }
    for (int i = gid; i < OUP; i += stp) {
        float s3 = g3[i] * rsqrtf(v3[i] + EPSV);
        be3o[i] = b3[i] - m3[i] * s3;
    }
    for (int i = gid; i < BATCH * HWSZ; i += stp) {     // mf + 3x3 dilated md
        int b = i / HWSZ, p = i - b * HWSZ;
        int y = p / WW, xx = p - y * WW;
        float mf = (float)mask[i];
        float md = 0.f;
        for (int dy = -1; dy <= 1; ++dy)
            for (int dx = -1; dx <= 1; ++dx) {
                int yy = y + dy, xc = xx + dx;
                if (yy >= 0 && yy < HH && xc >= 0 && xc < WW)
                    md = fmaxf(md, (float)mask[b * HWSZ + yy * WW + xc]);
            }
        mff[i] = mf;
        mdf[i] = md;
    }
}

// ---------------- K1: expand GEMM -> h1 (bf16 pair-interleaved [b][c/2][p]) — r10/r13 proven ----------------
__launch_bounds__(512, 4)
__global__ void k1_expand(const float* __restrict__ x,
                          const unsigned short* __restrict__ w1f,
                          const float* __restrict__ be1g,
                          const float* __restrict__ mdf,
                          unsigned* __restrict__ h1p)
{
    __shared__ unsigned short xs[128 * 128];   // 32 KB  bf16 x-tile [px][c] swizzled
    const int t = threadIdx.x, lane = t & 63, wv = t >> 6;
    const int g = lane >> 4, r16 = lane & 15;
    const int pid = blockIdx.x;
    const int l = (pid & 7) * 150 + (pid >> 3);
    const int hb = l % 3;
    const int pb = (l / 3) % 25;
    const int b  = l / 75;
    const int p0 = pb * 128;
    const int whid = wv & 3;
    const int wpx  = wv >> 2;

    for (int rep = 0; rep < 8; ++rep) {
        int id = t + rep * 512;
        int px = id & 127, c4 = id >> 7;
        int p = p0 + px;
        ushort4 u; u.x = 0; u.y = 0; u.z = 0; u.w = 0;
        if (p < HWSZ) {
            const float* xp = x + ((size_t)(b * INP + c4 * 4)) * HWSZ + p;
            unsigned lo = pkbf(xp[0], xp[HWSZ]);
            unsigned hi = pkbf(xp[2 * HWSZ], xp[3 * HWSZ]);
            u.x = (unsigned short)lo; u.y = (unsigned short)(lo >> 16);
            u.z = (unsigned short)hi; u.w = (unsigned short)(hi >> 16);
        }
        *(ushort4*)&xs[px * 128 + (((c4 >> 1) ^ (px & 15)) << 3) + ((c4 & 1) << 2)] = u;
    }
    __syncthreads();

    f32x4 acc[4][4];
    #pragma unroll
    for (int mt = 0; mt < 4; ++mt)
        #pragma unroll
        for (int nt = 0; nt < 4; ++nt) {
            acc[mt][nt][0] = 0.f; acc[mt][nt][1] = 0.f;
            acc[mt][nt][2] = 0.f; acc[mt][nt][3] = 0.f;
        }
    const int hbase = hb * 256 + whid * 64;
    const int htb = hbase >> 4;

    #pragma unroll
    for (int ks = 0; ks < 4; ++ks) {
        bf16x8 af[4];
        #pragma unroll
        for (int mt = 0; mt < 4; ++mt)
            af[mt] = *(const bf16x8*)&w1f[((((htb + mt) * 4 + ks) * 64) + lane) << 3];
        #pragma unroll
        for (int nt = 0; nt < 4; ++nt) {
            int px = wpx * 64 + nt * 16 + r16;
            bf16x8 bf = *(const bf16x8*)&xs[px * 128 + (((ks * 4 + g) ^ r16) << 3)];
            #pragma unroll
            for (int mt = 0; mt < 4; ++mt)
                acc[mt][nt] = __builtin_amdgcn_mfma_f32_16x16x32_bf16(af[mt], bf, acc[mt][nt], 0, 0, 0);
        }
    }

    #pragma unroll
    for (int nt = 0; nt < 4; ++nt) {
        const int pg = p0 + wpx * 64 + nt * 16;
        if (pg >= HWSZ) continue;
        const int p = pg + r16;
        const float md = mdf[b * HWSZ + p];
        #pragma unroll
        for (int mt = 0; mt < 4; ++mt) {
            const float4 be4 = *(const float4*)&be1g[hbase + mt * 16 + g * 4];
            f32x4 a = acc[mt][nt];
            float v0 = fminf(fmaxf(a[0] + be4.x, 0.f), 6.f) * md;
            float v1 = fminf(fmaxf(a[1] + be4.y, 0.f), 6.f) * md;
            float v2 = fminf(fmaxf(a[2] + be4.z, 0.f), 6.f) * md;
            float v3 = fminf(fmaxf(a[3] + be4.w, 0.f), 6.f) * md;
            const int c2 = (hbase >> 1) + mt * 8 + g * 2;
            const size_t ad = (size_t)(b * 384 + c2) * HWSZ + p;
            h1p[ad] = pkbf(v0, v1);
            h1p[ad + HWSZ] = pkbf(v2, v3);
        }
    }
}

// ---------------- K23: r13 structure + s_setprio around P MFMA cluster (T5) ----------------
__launch_bounds__(512, 4)
__global__ void k23(const unsigned* __restrict__ h1p,
                    const unsigned short* __restrict__ w2f,
                    const float* __restrict__ wdsf,
                    const float* __restrict__ be2g,
                    const float* __restrict__ be3g,
                    const float* __restrict__ mff,
                    const float* __restrict__ x,
                    float* __restrict__ out)
{
    __shared__ unsigned stg[4 * RWST];           // 31872 B  h1 rows [row 4][cp 32 x 62 dw]
    __shared__ unsigned short h2s[112 * H2STR];  // 16128 B  h2 [px][c] swizzled
    __shared__ float mfv_[112];                  //   448 B

    const int t = threadIdx.x, lane = t & 63, wv = t >> 6;
    const int g = lane >> 4, r16 = lane & 15;
    const int pid = blockIdx.x;
    const int l = (pid & 7) * 56 + (pid >> 3);   // XCD swizzle (448 = 8*56)
    const int strip = l % 28, b = l / 28;
    const int y0 = strip * 2, p0 = strip * 112;

    // ---------------- prologue ----------------
    if (t < 112) mfv_[t] = mff[b * HWSZ + p0 + t];
    if (t >= 128 && t < 384) {   // zero stg edge dwords (px=-1 at off 1, px=56 at off 58)
        int i = t - 128;
        int cp = i & 31, rs = (i >> 5) & 3, side = (i >> 7) & 1;
        stg[rs * RWST + cp * 62 + (side ? 58 : 1)] = 0;
    }

    // T14 stage state: 1792 tasks = cp32 x row4 x px4_14
    int gaddr[4], laddr[4]; bool gval[4], wval[4];
    #pragma unroll
    for (int rep = 0; rep < 4; ++rep) {
        const int id = t + rep * 512;
        const int rr  = (id * 4682) >> 16;            // id/14
        const int px4 = id - rr * 14;
        const int row = rr & 3, cp = rr >> 2;
        const int gy = y0 - 1 + row;
        wval[rep] = id < 1792;
        gval[rep] = wval[rep] && gy >= 0 && gy < HH;
        gaddr[rep] = (b * 384 + cp) * HWSZ + gy * WW + px4 * 4;
        laddr[rep] = row * RWST + cp * 62 + 2 + px4 * 4;
    }
    uint4 sreg[4];

    auto issueLoads = [&]() {
        #pragma unroll
        for (int rep = 0; rep < 4; ++rep) {
            uint4 u; u.x = 0; u.y = 0; u.z = 0; u.w = 0;
            if (gval[rep]) u = *(const uint4*)&h1p[gaddr[rep]];
            sreg[rep] = u;
            gaddr[rep] += 32 * HWSZ;                  // next chunk (+32 cp)
        }
    };
    auto stageWrite = [&]() {
        #pragma unroll
        for (int rep = 0; rep < 4; ++rep) {
            if (wval[rep]) {
                unsigned* s = &stg[laddr[rep]];
                uint2 a; a.x = sreg[rep].x; a.y = sreg[rep].y;
                uint2 c; c.x = sreg[rep].z; c.y = sreg[rep].w;
                *(uint2*)(s) = a;
                *(uint2*)(s + 2) = c;
            }
        }
    };

    // DW mapping: thread -> (cp 32, row2 2, q 8); 2 paired channels x 7 px each
    const int cp_c = t & 31, row2 = (t >> 5) & 1, q = t >> 6;   // q == wave id
    unsigned* const h2d = (unsigned*)h2s;

    auto phaseDW = [&](int ch) {
        const float2 be2 = *(const float2*)&be2g[ch * 64 + 2 * cp_c];
        float accL[7], accH[7];
        #pragma unroll
        for (int j = 0; j < 7; ++j) { accL[j] = be2.x; accH[j] = be2.y; }
        #pragma unroll
        for (int dy = 0; dy < 3; ++dy) {
            const float2 wt0 = *(const float2*)&wdsf[(dy * 3 + 0) * HID + ch * 64 + 2 * cp_c];
            const float2 wt1 = *(const float2*)&wdsf[(dy * 3 + 1) * HID + ch * 64 + 2 * cp_c];
            const float2 wt2 = *(const float2*)&wdsf[(dy * 3 + 2) * HID + ch * 64 + 2 * cp_c];
            const unsigned* rp = &stg[(row2 + dy) * RWST + cp_c * 62 + 1 + q * 7];
            float pL[9], pH[9];
            #pragma unroll
            for (int k = 0; k < 9; ++k) {
                unsigned u = rp[k];
                pL[k] = blo(u); pH[k] = bhi(u);
            }
            #pragma unroll
            for (int j = 0; j < 7; ++j) {
                accL[j] += pL[j] * wt0.x + pL[j + 1] * wt1.x + pL[j + 2] * wt2.x;
                accH[j] += pH[j] * wt0.y + pH[j + 1] * wt1.y + pH[j + 2] * wt2.y;
            }
        }
        #pragma unroll
        for (int j = 0; j < 7; ++j) {
            const int px = row2 * 56 + q * 7 + j;
            const float mv = mfv_[px];
            float vL = __builtin_amdgcn_fmed3f(accL[j], 0.f, 6.f) * mv;
            float vH = __builtin_amdgcn_fmed3f(accH[j], 0.f, 6.f) * mv;
            // full-dword write at P-read-compatible slot: octet (cp>>2)^(px&7), dword (cp&3)
            h2d[px * 36 + (((cp_c >> 2) ^ (px & 7)) << 2) + (cp_c & 3)] = pkbf(vL, vH);
        }
    };

    f32x4 pacc[7];
    #pragma unroll
    for (int nt = 0; nt < 7; ++nt) {
        pacc[nt][0] = 0.f; pacc[nt][1] = 0.f; pacc[nt][2] = 0.f; pacc[nt][3] = 0.f;
    }

    auto phaseP = [&](int ch) {
        __builtin_amdgcn_s_setprio(1);        // T5: favor MFMA-phase waves vs co-resident DW waves
        #pragma unroll
        for (int ks = 0; ks < 2; ++ks) {
            const bf16x8 pw = *(const bf16x8*)&w2f[((((wv * 12 + ch) * 2 + ks) * 64) + lane) << 3];
            #pragma unroll
            for (int nt = 0; nt < 7; ++nt) {
                const int px = nt * 16 + r16;
                const bf16x8 hb = *(const bf16x8*)&h2s[px * H2STR + (((ks * 4 + g) ^ (px & 7)) << 3)];
                pacc[nt] = __builtin_amdgcn_mfma_f32_16x16x32_bf16(pw, hb, pacc[nt], 0, 0, 0);
            }
        }
        __builtin_amdgcn_s_setprio(0);
    };

    // ---- main loop: loads for ch+1 fly under DW(ch); write lands under P(ch) ----
    issueLoads();
    stageWrite();
    __syncthreads();
    for (int ch = 0; ch < 12; ++ch) {
        if (ch + 1 < 12) issueLoads();
        phaseDW(ch);
        __syncthreads();                      // stg reads done; h2s written
        if (ch + 1 < 12) stageWrite();
        phaseP(ch);
        __syncthreads();                      // stg ready; h2s free
    }

    // ---- epilogue: out = x + (proj + be3) * mf ----
    {
        const int ob = wv * 16 + g * 4;
        const float4 be4 = *(const float4*)&be3g[ob];
        #pragma unroll
        for (int nt = 0; nt < 7; ++nt) {
            const int px = nt * 16 + r16;
            const float mv = mfv_[px];
            const size_t base = (size_t)(b * OUP + ob) * HWSZ + p0 + px;
            out[base]            = x[base]            + (pacc[nt][0] + be4.x) * mv;
            out[base + HWSZ]     = x[base + HWSZ]     + (pacc[nt][1] + be4.y) * mv;
            out[base + 2 * HWSZ] = x[base + 2 * HWSZ] + (pacc[nt][2] + be4.z) * mv;
            out[base + 3 * HWSZ] = x[base + 3 * HWSZ] + (pacc[nt][3] + be4.w) * mv;
        }
    }
}

extern "C" void kernel_launch(void* const* d_in, const int* in_sizes, int n_in,
                              void* d_out, int out_size, void* d_ws, size_t ws_size,
                              hipStream_t stream) {
    (void)in_sizes; (void)n_in; (void)out_size; (void)ws_size;
    const float* x   = (const float*)d_in[0];
    const float* w1  = (const float*)d_in[1];
    const float* g1  = (const float*)d_in[2];
    const float* b1  = (const float*)d_in[3];
    const float* m1  = (const float*)d_in[4];
    const float* v1  = (const float*)d_in[5];
    const float* wdw = (const float*)d_in[6];
    const float* g2  = (const float*)d_in[7];
    const float* b2  = (const float*)d_in[8];
    const float* m2  = (const float*)d_in[9];
    const float* v2  = (const float*)d_in[10];
    const float* w2  = (const float*)d_in[11];
    const float* g3  = (const float*)d_in[12];
    const float* b3  = (const float*)d_in[13];
    const float* m3  = (const float*)d_in[14];
    const float* v3  = (const float*)d_in[15];
    const int*  mask = (const int*)d_in[16];
    float* out = (float*)d_out;

    char* ws = (char*)d_ws;
    unsigned short* w1f = (unsigned short*)ws;                 // 196608 B
    unsigned short* w2f = (unsigned short*)(ws + 196608);      // 196608 B
    float* be1o = (float*)(ws + 393216);                       // 3072 B
    float* wdsf = (float*)(ws + 396288);                       // 27648 B  [9][768]
    float* be2o = (float*)(ws + 423936);                       // 3072 B
    float* be3o = (float*)(ws + 427008);                       // 512 B
    float* mdf  = (float*)(ws + 427520);                       // 200704 B
    float* mff  = (float*)(ws + 628224);                       // 200704 B
    unsigned* h1p = (unsigned*)(ws + 828928);                  // 77070336 B (bf16 pairs)

    // prep is TLP-starved at 256 blocks (~8 items/thread, 9 dependent loads each);
    // 1024 blocks = 262K threads brings it to ~2 items/thread (G11 memory-bound sizing)
    prep<<<1024, 256, 0, stream>>>(w1, g1, b1, m1, v1, wdw, g2, b2, m2, v2,
                                   w2, g3, b3, m3, v3, mask,
                                   w1f, w2f, be1o, wdsf, be2o, be3o, mdf, mff);
    k1_expand<<<dim3(1200), 512, 0, stream>>>(x, w1f, be1o, mdf, h1p);
    k23<<<dim3(448), 512, 0, stream>>>(h1p, w2f, wdsf, be2o, be3o, mff, x, out);
}